// Round 13
// baseline (312.556 us; speedup 1.0000x reference)
//
#include <hip/hip_runtime.h>
#include <stdint.h>

typedef __attribute__((ext_vector_type(8))) short short8;
typedef __attribute__((ext_vector_type(4))) float f32x4;

#define T_STEPS 256
#define BATCH   128

// LDS-visibility barrier that does NOT drain vmcnt (global X prefetch stays in flight)
#define LDS_BARRIER() asm volatile("s_waitcnt lgkmcnt(0)\n\ts_barrier" ::: "memory")

static __device__ inline unsigned short f2bf(float f) {   // RNE fp32->bf16 (W2 hi/lo path)
    unsigned int u = __float_as_uint(f);
    unsigned int r = u + 0x7FFFu + ((u >> 16) & 1u);
    return (unsigned short)(r >> 16);
}
// pack_hi16(a,b) = (a>>16) | (b & 0xFFFF0000)  -> single v_perm_b32
static __device__ inline unsigned pack_hi16(unsigned a, unsigned b) {
    return __builtin_amdgcn_perm(b, a, 0x07060302u);
}
// async global->LDS DMA: per-lane global addr, wave-uniform LDS base (+lane*16 in HW)
static __device__ inline void gload_lds16(const unsigned short* g, unsigned short* l) {
    __builtin_amdgcn_global_load_lds(
        (const __attribute__((address_space(1))) unsigned int*)(const void*)g,
        (__attribute__((address_space(3))) unsigned int*)(void*)l,
        16, 0, 0);
}

// ---- k_prep: blocks 0..255 -> W2 hi/lo split; 256..257 -> W1 3-split rows (scaled 1/thr1);
//      blocks 258..513 -> X compact half-fragments (normalized, exact 3-way bf16 trunc split)
// Also zeroes the k_act last-block counter (graph replay safe: runs every iteration).
__global__ __launch_bounds__(256) void k_prep(
    const float* __restrict__ W2, const float* __restrict__ W1,
    const float* __restrict__ b1, const float* __restrict__ thr1,
    const float* __restrict__ imin_p, const float* __restrict__ imax_p,
    const float* __restrict__ batch,
    unsigned short* __restrict__ W2hi, unsigned short* __restrict__ W2lo,
    unsigned short* __restrict__ W1rows, float* __restrict__ b1s,
    unsigned short* __restrict__ Xf, unsigned int* __restrict__ cnt)
{
    int blk = blockIdx.x, tid = threadIdx.x;
    if (blk == 0 && tid == 0) cnt[0] = 0u;
    if (blk < 256) {
        int gid = blk * 256 + tid;          // 65536 threads, 4 elems each
        f32x4 wv = *(const f32x4*)(W2 + (size_t)gid * 4);
        unsigned short hi[4], lo[4];
#pragma unroll
        for (int e = 0; e < 4; ++e) {
            float wf = wv[e];
            unsigned short h = f2bf(wf);
            float hf = __uint_as_float(((unsigned int)h) << 16);
            hi[e] = h;
            lo[e] = f2bf(wf - hf);
        }
        uint2 ph, pl;
        ph.x = (unsigned)hi[0] | ((unsigned)hi[1] << 16);
        ph.y = (unsigned)hi[2] | ((unsigned)hi[3] << 16);
        pl.x = (unsigned)lo[0] | ((unsigned)lo[1] << 16);
        pl.y = (unsigned)lo[2] | ((unsigned)lo[3] << 16);
        *(uint2*)(W2hi + (size_t)gid * 4) = ph;
        *(uint2*)(W2lo + (size_t)gid * 4) = pl;
    } else if (blk < 258) {
        int h = (blk - 256) * 256 + tid;    // 512 rows
        float wsc = 1.0f / thr1[h];
        unsigned short row[64];
#pragma unroll
        for (int k = 0; k < 16; ++k) {
            float wv = W1[h * 16 + k] * wsc;
            unsigned a = __float_as_uint(wv) & 0xFFFF0000u;
            float r1 = wv - __uint_as_float(a);
            unsigned m = __float_as_uint(r1) & 0xFFFF0000u;
            float r2 = r1 - __uint_as_float(m);
            unsigned l = __float_as_uint(r2) & 0xFFFF0000u;
            row[k]      = (unsigned short)(a >> 16);
            row[16 + k] = (unsigned short)(m >> 16);
            row[32 + k] = (unsigned short)(l >> 16);
            row[48 + k] = 0;
        }
        b1s[h] = b1[h] * wsc;
        uint4* dst = (uint4*)(W1rows + (size_t)h * 64);
#pragma unroll
        for (int i = 0; i < 8; ++i) dst[i] = ((uint4*)row)[i];
    } else {
        int gid    = (blk - 258) * 256 + tid;   // 65536 = 256t * 8btile * 32lane
        int lane32 = gid & 31;
        int btile  = (gid >> 5) & 7;
        int t      = gid >> 8;
        int q1 = lane32 >> 4, m15 = lane32 & 15;
        int b  = btile * 16 + m15;
        float imin = imin_p[0];
        float isc  = 1.0f / (imax_p[0] - imin);
        const float* xp = batch + ((size_t)b * T_STEPS + t) * 16 + q1 * 8;
        unsigned uh[8], um[8], ul[8];
#pragma unroll
        for (int j = 0; j < 8; ++j) {
            float xv = (xp[j] - imin) * isc;
            unsigned a = __float_as_uint(xv) & 0xFFFF0000u;
            float r1 = xv - __uint_as_float(a);
            unsigned m = __float_as_uint(r1) & 0xFFFF0000u;
            float r2 = r1 - __uint_as_float(m);
            unsigned l = __float_as_uint(r2) & 0xFFFF0000u;
            uh[j] = a; um[j] = m; ul[j] = l;
        }
        uint4 XH, XM, XL;
        XH.x = pack_hi16(uh[0], uh[1]); XH.y = pack_hi16(uh[2], uh[3]);
        XH.z = pack_hi16(uh[4], uh[5]); XH.w = pack_hi16(uh[6], uh[7]);
        XM.x = pack_hi16(um[0], um[1]); XM.y = pack_hi16(um[2], um[3]);
        XM.z = pack_hi16(um[4], um[5]); XM.w = pack_hi16(um[6], um[7]);
        XL.x = pack_hi16(ul[0], ul[1]); XL.y = pack_hi16(ul[2], ul[3]);
        XL.z = pack_hi16(ul[4], ul[5]); XL.w = pack_hi16(ul[6], ul[7]);
        unsigned short* dst = Xf + ((size_t)t * 8 + btile) * 1024 + lane32 * 8;
        *(uint4*)(dst +   0) = XH;
        *(uint4*)(dst + 256) = XM;
        *(uint4*)(dst + 512) = XL;
    }
}

union XF { uint4 u; short8 s; };

// ---- main: 1024 threads (16 waves, 4/SIMD), K split 16 ways — R12-exact (proven 199us)
// R2 pair-barrier cadence + k-permuted GEMM2 feed (no Aw LDS round-trip).
// Scheduler window hard-bounded: #pragma unroll 1 over PAIRS with runtime slot indices.
__global__ __launch_bounds__(1024, 4) void k_main(
    const unsigned short* __restrict__ Xf,
    const unsigned short* __restrict__ W2hi, const unsigned short* __restrict__ W2lo,
    const unsigned short* __restrict__ W1rows, const float* __restrict__ b1s,
    const float* __restrict__ beta1, const float* __restrict__ b2,
    const float* __restrict__ beta2, const float* __restrict__ thr2,
    unsigned short* __restrict__ spkbits)
{
    __shared__ float Cbuf[4][4096];       // [slot][r 4][wp 16][lane 64]  (64 KB)
    __shared__ unsigned short Xs[8192];   // X ring: 8 slots x 1024 shorts (2KB)

    int tid  = threadIdx.x;
    int lane = tid & 63;
    int w    = tid >> 6;                  // 0..15: K-chunk of 32 (and GEMM1 h-chunk of 32)
    int q = lane >> 4, m15 = lane & 15;
    int btile = blockIdx.x & 7;
    int slice = blockIdx.x >> 3;

    // W1 A-frags: A1=[Wh|Wm], A2=[Wh|Wl], A3=[Wm|Wl]
    short8 A1[2], A2[2], A3[2];
#pragma unroll
    for (int c = 0; c < 2; ++c) {
        const unsigned short* rp = W1rows + (size_t)(w * 32 + c * 16 + m15) * 64;
        A1[c] = *(const short8*)(rp + q * 8);
        A2[c] = *(const short8*)(rp + q * 8 + (q >> 1) * 16);
        A3[c] = *(const short8*)(rp + 16 + q * 8);
    }
    // W2 B-frags for K-window [w*32, w*32+32), k-permuted order:
    // element j of lane q = W2[jg][w*32 + (j>>2)*16 + q*4 + (j&3)]   (R10/R12-verified)
    int jg = slice * 16 + m15;
    short8 bhi, blo;
    {
        const unsigned short* ph = W2hi + (size_t)jg * 512 + w * 32 + q * 4;
        const unsigned short* pl = W2lo + (size_t)jg * 512 + w * 32 + q * 4;
        uint2 h0 = *(const uint2*)(ph);
        uint2 h1 = *(const uint2*)(ph + 16);
        uint2 l0 = *(const uint2*)(pl);
        uint2 l1 = *(const uint2*)(pl + 16);
        union { uint4 u; short8 s; } tb;
        tb.u.x = h0.x; tb.u.y = h0.y; tb.u.z = h1.x; tb.u.w = h1.y;
        bhi = tb.s;
        tb.u.x = l0.x; tb.u.y = l0.y; tb.u.z = l1.x; tb.u.w = l1.y;
        blo = tb.s;
    }

    // LIF1 params: states (b=m15, h = w*32 + c*16 + q*4 + r)
    f32x4 b14[2], bet1[2];
#pragma unroll
    for (int c = 0; c < 2; ++c) {
        int h0 = w * 32 + c * 16 + q * 4;
        b14[c] = *(const f32x4*)(b1s + h0);
        f32x4 bb = *(const f32x4*)(beta1 + h0);
#pragma unroll
        for (int r = 0; r < 4; ++r) bet1[c][r] = fminf(fmaxf(bb[r], 0.0f), 1.0f);
    }
    float m1[8], spk1f[8];
#pragma unroll
    for (int i = 0; i < 8; ++i) { m1[i] = 0.0f; spk1f[i] = 0.0f; }

    // LIF2 (waves 0..3): item (b = q*4 + w, j = jg) — scalar state only
    float beta2r = fminf(fmaxf(beta2[jg], 0.0f), 1.0f);
    float thr2r  = thr2[jg];
    float nthr2  = -thr2r;
    float b2r    = b2[jg];
    float m2 = 0.0f, spk2f = 0.0f;

    // X: per-lane DMA source base + LDS frag offsets (shorts)
    const unsigned short* xgbase = Xf + (size_t)btile * 1024 + (size_t)lane * 8;
    int l31x8 = (lane & 31) * 8;
    int o1 = l31x8;                                  // B1=[xh|xh]  (2-way broadcast)
    int o2 = l31x8 + 256;                            // B2=[xm|xm]
    int o3 = l31x8 + (lane < 32 ? 512 : 0);          // B3=[xl|xh]
    int o4 = l31x8 + (lane < 32 ? 512 : 256);        // B4=[xl|xm]

    // prologue: stage X(0..3) into ring slots 0..3
    if (w == 15) {
#pragma unroll
        for (int s = 0; s < 4; ++s) {
            gload_lds16(xgbase + (size_t)s * 8192,       Xs + s * 1024);
            gload_lds16(xgbase + (size_t)s * 8192 + 512, Xs + s * 1024 + 512);
        }
        asm volatile("s_waitcnt vmcnt(0)" ::: "memory");
    }
    __syncthreads();

    XF xc[4], xn[4];
    {
        const unsigned short* s = Xs;                // slot 0 = X(0)
        xc[0].u = *(const uint4*)(s + o1);
        xc[1].u = *(const uint4*)(s + o2);
        xc[2].u = *(const uint4*)(s + o3);
        xc[3].u = *(const uint4*)(s + o4);
    }

    auto reduce_one = [&](int slot, int step) __attribute__((always_inline)) {
        float cur2 = b2r;
#pragma unroll
        for (int wp = 0; wp < 16; ++wp) cur2 += Cbuf[slot][w * 1024 + wp * 64 + lane];
        m2 = fmaf(beta2r, m2, cur2);
        m2 = fmaf(spk2f, nthr2, m2);
        bool sp2 = m2 > thr2r;
        spk2f = sp2 ? 1.0f : 0.0f;
        unsigned long long mask = __ballot(sp2);
        if (lane < 4) {
            unsigned short v = (unsigned short)(mask >> (lane * 16));
            spkbits[((size_t)step * BATCH + btile * 16 + lane * 4 + w) * 32 + slice] = v;
        }
    };

    auto body = [&](int step, XF* xcur, XF* xnx) __attribute__((always_inline)) {
        // register-prefetch X(step+1) frags from ring slot (step+1)&7 (runtime index)
        {
            const unsigned short* sx = Xs + (size_t)(((step + 1) & 7) * 1024);
            xnx[0].u = *(const uint4*)(sx + o1);
            xnx[1].u = *(const uint4*)(sx + o2);
            xnx[2].u = *(const uint4*)(sx + o3);
            xnx[3].u = *(const uint4*)(sx + o4);
        }
        // GEMM1: 4-term split, 8 MFMA (C initialized directly from bias)
        f32x4 D[2];
#pragma unroll
        for (int c = 0; c < 2; ++c) {
            D[c] = __builtin_amdgcn_mfma_f32_16x16x32_bf16(A1[c], xcur[0].s, b14[c], 0, 0, 0);
            D[c] = __builtin_amdgcn_mfma_f32_16x16x32_bf16(A1[c], xcur[1].s, D[c], 0, 0, 0);
            D[c] = __builtin_amdgcn_mfma_f32_16x16x32_bf16(A2[c], xcur[2].s, D[c], 0, 0, 0);
            D[c] = __builtin_amdgcn_mfma_f32_16x16x32_bf16(A3[c], xcur[3].s, D[c], 0, 0, 0);
        }
        // LIF1 (scaled: thr == 1)
#pragma unroll
        for (int i = 0; i < 8; ++i) {
            int c = i >> 2, r = i & 3;
            float mv = fmaf(bet1[c][r], m1[i], D[c][r]);
            mv -= spk1f[i];
            bool sp = mv > 1.0f;
            m1[i] = mv;
            spk1f[i] = sp ? 1.0f : 0.0f;
        }
        // spikes pack directly into GEMM2's A-frag (k-permuted window: af[j] = spk1f[j])
        union { uint4 u; short8 s; } af;
        af.u.x = pack_hi16(__float_as_uint(spk1f[0]), __float_as_uint(spk1f[1]));
        af.u.y = pack_hi16(__float_as_uint(spk1f[2]), __float_as_uint(spk1f[3]));
        af.u.z = pack_hi16(__float_as_uint(spk1f[4]), __float_as_uint(spk1f[5]));
        af.u.w = pack_hi16(__float_as_uint(spk1f[6]), __float_as_uint(spk1f[7]));
        // GEMM2: K=32 chunk, hi then lo chained
        f32x4 C2 = { 0.f, 0.f, 0.f, 0.f };
        C2 = __builtin_amdgcn_mfma_f32_16x16x32_bf16(af.s, bhi, C2, 0, 0, 0);
        C2 = __builtin_amdgcn_mfma_f32_16x16x32_bf16(af.s, blo, C2, 0, 0, 0);
        float* cb = Cbuf[step & 3];
#pragma unroll
        for (int r = 0; r < 4; ++r)
            cb[r * 1024 + w * 64 + lane] = C2[r];
    };

#pragma unroll 1
    for (int p = 0; p < T_STEPS / 2; ++p) {
        int s0 = p << 1;
        // stager: DMA X(s0+4), X(s0+5) into ring slots (s0+4)&7, (s0+5)&7 (R2 cadence)
        if (w == 15) {
            int ta = s0 + 4; if (ta > T_STEPS - 1) ta = T_STEPS - 1;
            int tb = s0 + 5; if (tb > T_STEPS - 1) tb = T_STEPS - 1;
            const unsigned short* ga = xgbase + (size_t)ta * 8192;
            const unsigned short* gb = xgbase + (size_t)tb * 8192;
            unsigned short* la = Xs + (size_t)(((s0 + 4) & 7) * 1024);
            unsigned short* lb = Xs + (size_t)(((s0 + 5) & 7) * 1024);
            gload_lds16(ga,       la);
            gload_lds16(ga + 512, la + 512);
            gload_lds16(gb,       lb);
            gload_lds16(gb + 512, lb + 512);
        }
        // waves 0-3: reduce previous pair (steps s0-2, s0-1) while others run ahead
        if (w < 4 && p > 0) {
            reduce_one((s0 + 2) & 3, s0 - 2);
            reduce_one((s0 + 3) & 3, s0 - 1);
        }
        body(s0,     xc, xn);
        body(s0 + 1, xn, xc);
        if (w == 15) asm volatile("s_waitcnt vmcnt(0)" ::: "memory");
        LDS_BARRIER();
    }
    // epilogue: last pair (steps 254,255 -> Cbuf slots 2,3)
    if (w < 4) {
        reduce_one(2, T_STEPS - 2);
        reduce_one(3, T_STEPS - 1);
    }
}

// ---- action bit-GEMM + beta-weighted scan over t, 2 time-chunks, fused carry fix-up ----
// grid 256 = (b 128) x (chunk 2); 512 threads = (tl 128) x (s 4).
// chunk 0 writes out[t<128] + carry[b]; chunk 1 writes local scans to Lws.
// LAST block (atomic counter) applies out[t>=128] = Lws + beta^(tl+1)*carry — replaces k_act2.
__global__ __launch_bounds__(512) void k_act(
    const unsigned short* __restrict__ spkbits,
    const float* __restrict__ Wa, const float* __restrict__ ba,
    const float* __restrict__ beta_act_p, float* __restrict__ out,
    f32x4* __restrict__ Lws, f32x4* __restrict__ Cws, unsigned int* __restrict__ cnt)
{
    __shared__ f32x4 waT[512];
    __shared__ f32x4 part[512];
    __shared__ f32x4 sc[128];
    __shared__ unsigned int lastFlag;
    int tid = threadIdx.x;
    int b   = blockIdx.x & 127;
    int c   = blockIdx.x >> 7;
    int tl  = tid & 127;
    int s   = tid >> 7;          // 0..3
    int t   = c * 128 + tl;

    {
        f32x4 v = { Wa[tid], Wa[512 + tid], Wa[1024 + tid], Wa[1536 + tid] };
        waT[tid] = v;
    }
    float bact = fminf(fmaxf(beta_act_p[0], 0.0f), 1.0f);
    f32x4 acc;
    if (s == 0) { acc[0] = ba[0]; acc[1] = ba[1]; acc[2] = ba[2]; acc[3] = ba[3]; }
    else        { acc[0] = 0.f;   acc[1] = 0.f;   acc[2] = 0.f;   acc[3] = 0.f;   }
    __syncthreads();

    // this thread: timestep t, segments [s*8, s*8+8) (each segment = 16 j bits)
    const unsigned short* sp = spkbits + ((size_t)t * BATCH + b) * 32 + s * 8;
    uint4 v = *(const uint4*)sp;
    unsigned int wbuf[4] = { v.x, v.y, v.z, v.w };
#pragma unroll
    for (int ww = 0; ww < 4; ++ww) {
#pragma unroll
        for (int half = 0; half < 2; ++half) {
            unsigned int wd = (wbuf[ww] >> (half * 16)) & 0xFFFFu;
            int seg = s * 8 + ww * 2 + half;
#pragma unroll
            for (int i = 0; i < 16; ++i) {
                float sel = ((wd >> i) & 1u) ? 1.0f : 0.0f;
                f32x4 wv = waT[seg * 16 + i];
                acc[0] = fmaf(sel, wv[0], acc[0]);
                acc[1] = fmaf(sel, wv[1], acc[1]);
                acc[2] = fmaf(sel, wv[2], acc[2]);
                acc[3] = fmaf(sel, wv[3], acc[3]);
            }
        }
    }
    part[tid] = acc;
    __syncthreads();
    if (tid < 128) {
        f32x4 a0 = part[tid], a1 = part[tid + 128], a2 = part[tid + 256], a3 = part[tid + 384];
        f32x4 sum;
        sum[0] = ((a0[0] + a1[0]) + a2[0]) + a3[0];
        sum[1] = ((a0[1] + a1[1]) + a2[1]) + a3[1];
        sum[2] = ((a0[2] + a1[2]) + a2[2]) + a3[2];
        sum[3] = ((a0[3] + a1[3]) + a2[3]) + a3[3];
        sc[tid] = sum;
    }
    __syncthreads();
    float bd = bact;
    for (int d = 1; d < 128; d <<= 1) {
        f32x4 cv = { 0.f, 0.f, 0.f, 0.f }, pv = { 0.f, 0.f, 0.f, 0.f };
        if (tid < 128) {
            cv = sc[tid];
            if (tid >= d) pv = sc[tid - d];
        }
        __syncthreads();
        if (tid < 128) {
            cv[0] = fmaf(bd, pv[0], cv[0]);
            cv[1] = fmaf(bd, pv[1], cv[1]);
            cv[2] = fmaf(bd, pv[2], cv[2]);
            cv[3] = fmaf(bd, pv[3], cv[3]);
            sc[tid] = cv;
        }
        __syncthreads();
        bd *= bd;
    }
    if (tid < 128) {
        f32x4 res = sc[tid];
        if (c == 0) {
            *(f32x4*)(out + (size_t)t * 512 + b * 4) = res;
            if (tl == 127) Cws[b] = res;       // carry = mem_a(127)
        } else {
            Lws[b * 128 + tl] = res;           // local scan
        }
    }

    // ---- fused fix-up: last block applies out[t>=128] = Lws + beta^(tl+1) * carry ----
    __threadfence();
    __syncthreads();
    if (tid == 0) lastFlag = (atomicAdd(cnt, 1u) == 255u) ? 1u : 0u;
    __syncthreads();
    if (lastFlag) {
        __threadfence();   // acquire: all other blocks' Lws/Cws writes visible
        for (int i = tid; i < 128 * 128; i += 512) {
            int bb = i >> 7, tl2 = i & 127;
            float p = 1.0f, base = bact;
            int e = tl2 + 1;
#pragma unroll
            for (int it = 0; it < 8; ++it) { if (e & 1) p *= base; base *= base; e >>= 1; }
            f32x4 L = Lws[bb * 128 + tl2];
            f32x4 C = Cws[bb];
            f32x4 r;
            r[0] = fmaf(p, C[0], L[0]);
            r[1] = fmaf(p, C[1], L[1]);
            r[2] = fmaf(p, C[2], L[2]);
            r[3] = fmaf(p, C[3], L[3]);
            *(f32x4*)(out + (size_t)(128 + tl2) * 512 + bb * 4) = r;
        }
    }
}

extern "C" void kernel_launch(void* const* d_in, const int* in_sizes, int n_in,
                              void* d_out, int out_size, void* d_ws, size_t ws_size,
                              hipStream_t stream)
{
    const float* batch    = (const float*)d_in[0];
    const float* W1       = (const float*)d_in[1];
    const float* b1       = (const float*)d_in[2];
    const float* beta1    = (const float*)d_in[3];
    const float* thr1     = (const float*)d_in[4];
    const float* W2       = (const float*)d_in[5];
    const float* b2       = (const float*)d_in[6];
    const float* beta2    = (const float*)d_in[7];
    const float* thr2     = (const float*)d_in[8];
    const float* Wa       = (const float*)d_in[9];
    const float* ba       = (const float*)d_in[10];
    const float* beta_act = (const float*)d_in[11];
    const float* inp_min  = (const float*)d_in[12];
    const float* inp_max  = (const float*)d_in[13];
    float* out            = (float*)d_out;

    char* ws = (char*)d_ws;
    unsigned short* W2hi    = (unsigned short*)ws;                          // 512 KiB
    unsigned short* W2lo    = (unsigned short*)(ws + (512u << 10));         // 512 KiB
    unsigned short* W1rows  = (unsigned short*)(ws + (1u << 20));           // 64 KiB
    float*          b1s     = (float*)(ws + (1u << 20) + (64u << 10));      // 2 KiB
    unsigned short* Xf      = (unsigned short*)(ws + (2u << 20));           // 4 MiB (compact)
    f32x4*          Lws     = (f32x4*)(ws + (6u << 20));                    // 256 KiB
    f32x4*          Cws     = (f32x4*)(ws + (6u << 20) + (256u << 10));     // 2 KiB
    unsigned int*   cnt     = (unsigned int*)(ws + (6u << 20) + (260u << 10)); // 4 B
    unsigned short* spkbits = (unsigned short*)(ws + (10u << 20));          // 2 MiB

    hipLaunchKernelGGL(k_prep, dim3(514), dim3(256), 0, stream,
                       W2, W1, b1, thr1, inp_min, inp_max, batch,
                       W2hi, W2lo, W1rows, b1s, Xf, cnt);
    hipLaunchKernelGGL(k_main, dim3(256), dim3(1024), 0, stream,
                       Xf, W2hi, W2lo, W1rows, b1s, beta1, b2, beta2, thr2, spkbits);
    hipLaunchKernelGGL(k_act, dim3(256), dim3(512), 0, stream,
                       spkbits, Wa, ba, beta_act, out, Lws, Cws, cnt);
}

// Round 14
// 255.166 us; speedup vs baseline: 1.2249x; 1.2249x over previous
//
#include <hip/hip_runtime.h>
#include <stdint.h>

typedef __attribute__((ext_vector_type(8))) short short8;
typedef __attribute__((ext_vector_type(4))) float f32x4;

#define T_STEPS 256
#define BATCH   128

// LDS-visibility barrier that does NOT drain vmcnt (global X prefetch stays in flight)
#define LDS_BARRIER() asm volatile("s_waitcnt lgkmcnt(0)\n\ts_barrier" ::: "memory")

static __device__ inline unsigned short f2bf(float f) {   // RNE fp32->bf16 (W2 hi/lo path)
    unsigned int u = __float_as_uint(f);
    unsigned int r = u + 0x7FFFu + ((u >> 16) & 1u);
    return (unsigned short)(r >> 16);
}
// pack_hi16(a,b) = (a>>16) | (b & 0xFFFF0000)  -> single v_perm_b32
static __device__ inline unsigned pack_hi16(unsigned a, unsigned b) {
    return __builtin_amdgcn_perm(b, a, 0x07060302u);
}
// async global->LDS DMA: per-lane global addr, wave-uniform LDS base (+lane*16 in HW)
static __device__ inline void gload_lds16(const unsigned short* g, unsigned short* l) {
    __builtin_amdgcn_global_load_lds(
        (const __attribute__((address_space(1))) unsigned int*)(const void*)g,
        (__attribute__((address_space(3))) unsigned int*)(void*)l,
        16, 0, 0);
}

// ---- k_prep: blocks 0..255 -> W2 hi/lo split; 256..257 -> W1 3-split rows (scaled 1/thr1);
//      blocks 258..513 -> X compact half-fragments (normalized, exact 3-way bf16 trunc split)
// W1rows[h][64]: [0..15]=Wh, [16..31]=Wm, [32..47]=Wl, [48..63]=0  (W' = W1 / thr1[h])
// Xf[t][btile]: 2KB slot (1024 shorts): [0,256)=xh half-frag, [256,512)=xm, [512,768)=xl, [768,1024)=pad
__global__ __launch_bounds__(256) void k_prep(
    const float* __restrict__ W2, const float* __restrict__ W1,
    const float* __restrict__ b1, const float* __restrict__ thr1,
    const float* __restrict__ imin_p, const float* __restrict__ imax_p,
    const float* __restrict__ batch,
    unsigned short* __restrict__ W2hi, unsigned short* __restrict__ W2lo,
    unsigned short* __restrict__ W1rows, float* __restrict__ b1s,
    unsigned short* __restrict__ Xf)
{
    int blk = blockIdx.x, tid = threadIdx.x;
    if (blk < 256) {
        int gid = blk * 256 + tid;          // 65536 threads, 4 elems each
        f32x4 wv = *(const f32x4*)(W2 + (size_t)gid * 4);
        unsigned short hi[4], lo[4];
#pragma unroll
        for (int e = 0; e < 4; ++e) {
            float wf = wv[e];
            unsigned short h = f2bf(wf);
            float hf = __uint_as_float(((unsigned int)h) << 16);
            hi[e] = h;
            lo[e] = f2bf(wf - hf);
        }
        uint2 ph, pl;
        ph.x = (unsigned)hi[0] | ((unsigned)hi[1] << 16);
        ph.y = (unsigned)hi[2] | ((unsigned)hi[3] << 16);
        pl.x = (unsigned)lo[0] | ((unsigned)lo[1] << 16);
        pl.y = (unsigned)lo[2] | ((unsigned)lo[3] << 16);
        *(uint2*)(W2hi + (size_t)gid * 4) = ph;
        *(uint2*)(W2lo + (size_t)gid * 4) = pl;
    } else if (blk < 258) {
        int h = (blk - 256) * 256 + tid;    // 512 rows
        float wsc = 1.0f / thr1[h];
        unsigned short row[64];
#pragma unroll
        for (int k = 0; k < 16; ++k) {
            float wv = W1[h * 16 + k] * wsc;
            unsigned a = __float_as_uint(wv) & 0xFFFF0000u;
            float r1 = wv - __uint_as_float(a);
            unsigned m = __float_as_uint(r1) & 0xFFFF0000u;
            float r2 = r1 - __uint_as_float(m);
            unsigned l = __float_as_uint(r2) & 0xFFFF0000u;
            row[k]      = (unsigned short)(a >> 16);
            row[16 + k] = (unsigned short)(m >> 16);
            row[32 + k] = (unsigned short)(l >> 16);
            row[48 + k] = 0;
        }
        b1s[h] = b1[h] * wsc;
        uint4* dst = (uint4*)(W1rows + (size_t)h * 64);
#pragma unroll
        for (int i = 0; i < 8; ++i) dst[i] = ((uint4*)row)[i];
    } else {
        int gid    = (blk - 258) * 256 + tid;   // 65536 = 256t * 8btile * 32lane
        int lane32 = gid & 31;
        int btile  = (gid >> 5) & 7;
        int t      = gid >> 8;
        int q1 = lane32 >> 4, m15 = lane32 & 15;
        int b  = btile * 16 + m15;
        float imin = imin_p[0];
        float isc  = 1.0f / (imax_p[0] - imin);
        const float* xp = batch + ((size_t)b * T_STEPS + t) * 16 + q1 * 8;
        unsigned uh[8], um[8], ul[8];
#pragma unroll
        for (int j = 0; j < 8; ++j) {
            float xv = (xp[j] - imin) * isc;
            unsigned a = __float_as_uint(xv) & 0xFFFF0000u;
            float r1 = xv - __uint_as_float(a);
            unsigned m = __float_as_uint(r1) & 0xFFFF0000u;
            float r2 = r1 - __uint_as_float(m);
            unsigned l = __float_as_uint(r2) & 0xFFFF0000u;
            uh[j] = a; um[j] = m; ul[j] = l;
        }
        uint4 XH, XM, XL;
        XH.x = pack_hi16(uh[0], uh[1]); XH.y = pack_hi16(uh[2], uh[3]);
        XH.z = pack_hi16(uh[4], uh[5]); XH.w = pack_hi16(uh[6], uh[7]);
        XM.x = pack_hi16(um[0], um[1]); XM.y = pack_hi16(um[2], um[3]);
        XM.z = pack_hi16(um[4], um[5]); XM.w = pack_hi16(um[6], um[7]);
        XL.x = pack_hi16(ul[0], ul[1]); XL.y = pack_hi16(ul[2], ul[3]);
        XL.z = pack_hi16(ul[4], ul[5]); XL.w = pack_hi16(ul[6], ul[7]);
        unsigned short* dst = Xf + ((size_t)t * 8 + btile) * 1024 + lane32 * 8;
        *(uint4*)(dst +   0) = XH;
        *(uint4*)(dst + 256) = XM;
        *(uint4*)(dst + 512) = XL;
    }
}

union XF { uint4 u; short8 s; };

// ---- main: 1024 threads (16 waves, 4/SIMD), K split 16 ways — R12-exact (proven ~195us)
// R2 pair-barrier cadence + k-permuted GEMM2 feed (no Aw LDS round-trip).
// Scheduler window hard-bounded: #pragma unroll 1 over PAIRS with runtime slot indices.
__global__ __launch_bounds__(1024, 4) void k_main(
    const unsigned short* __restrict__ Xf,
    const unsigned short* __restrict__ W2hi, const unsigned short* __restrict__ W2lo,
    const unsigned short* __restrict__ W1rows, const float* __restrict__ b1s,
    const float* __restrict__ beta1, const float* __restrict__ b2,
    const float* __restrict__ beta2, const float* __restrict__ thr2,
    unsigned short* __restrict__ spkbits)
{
    __shared__ float Cbuf[4][4096];       // [slot][r 4][wp 16][lane 64]  (64 KB)
    __shared__ unsigned short Xs[8192];   // X ring: 8 slots x 1024 shorts (2KB)

    int tid  = threadIdx.x;
    int lane = tid & 63;
    int w    = tid >> 6;                  // 0..15: K-chunk of 32 (and GEMM1 h-chunk of 32)
    int q = lane >> 4, m15 = lane & 15;
    int btile = blockIdx.x & 7;
    int slice = blockIdx.x >> 3;

    // W1 A-frags: A1=[Wh|Wm], A2=[Wh|Wl], A3=[Wm|Wl]
    short8 A1[2], A2[2], A3[2];
#pragma unroll
    for (int c = 0; c < 2; ++c) {
        const unsigned short* rp = W1rows + (size_t)(w * 32 + c * 16 + m15) * 64;
        A1[c] = *(const short8*)(rp + q * 8);
        A2[c] = *(const short8*)(rp + q * 8 + (q >> 1) * 16);
        A3[c] = *(const short8*)(rp + 16 + q * 8);
    }
    // W2 B-frags for K-window [w*32, w*32+32), k-permuted order:
    // element j of lane q = W2[jg][w*32 + (j>>2)*16 + q*4 + (j&3)]   (R10/R12-verified)
    int jg = slice * 16 + m15;
    short8 bhi, blo;
    {
        const unsigned short* ph = W2hi + (size_t)jg * 512 + w * 32 + q * 4;
        const unsigned short* pl = W2lo + (size_t)jg * 512 + w * 32 + q * 4;
        uint2 h0 = *(const uint2*)(ph);
        uint2 h1 = *(const uint2*)(ph + 16);
        uint2 l0 = *(const uint2*)(pl);
        uint2 l1 = *(const uint2*)(pl + 16);
        union { uint4 u; short8 s; } tb;
        tb.u.x = h0.x; tb.u.y = h0.y; tb.u.z = h1.x; tb.u.w = h1.y;
        bhi = tb.s;
        tb.u.x = l0.x; tb.u.y = l0.y; tb.u.z = l1.x; tb.u.w = l1.y;
        blo = tb.s;
    }

    // LIF1 params: states (b=m15, h = w*32 + c*16 + q*4 + r)
    f32x4 b14[2], bet1[2];
#pragma unroll
    for (int c = 0; c < 2; ++c) {
        int h0 = w * 32 + c * 16 + q * 4;
        b14[c] = *(const f32x4*)(b1s + h0);
        f32x4 bb = *(const f32x4*)(beta1 + h0);
#pragma unroll
        for (int r = 0; r < 4; ++r) bet1[c][r] = fminf(fmaxf(bb[r], 0.0f), 1.0f);
    }
    float m1[8], spk1f[8];
#pragma unroll
    for (int i = 0; i < 8; ++i) { m1[i] = 0.0f; spk1f[i] = 0.0f; }

    // LIF2 (waves 0..3): item (b = q*4 + w, j = jg) — scalar state only
    float beta2r = fminf(fmaxf(beta2[jg], 0.0f), 1.0f);
    float thr2r  = thr2[jg];
    float nthr2  = -thr2r;
    float b2r    = b2[jg];
    float m2 = 0.0f, spk2f = 0.0f;

    // X: per-lane DMA source base + LDS frag offsets (shorts)
    const unsigned short* xgbase = Xf + (size_t)btile * 1024 + (size_t)lane * 8;
    int l31x8 = (lane & 31) * 8;
    int o1 = l31x8;                                  // B1=[xh|xh]  (2-way broadcast)
    int o2 = l31x8 + 256;                            // B2=[xm|xm]
    int o3 = l31x8 + (lane < 32 ? 512 : 0);          // B3=[xl|xh]
    int o4 = l31x8 + (lane < 32 ? 512 : 256);        // B4=[xl|xm]

    // prologue: stage X(0..3) into ring slots 0..3
    if (w == 15) {
#pragma unroll
        for (int s = 0; s < 4; ++s) {
            gload_lds16(xgbase + (size_t)s * 8192,       Xs + s * 1024);
            gload_lds16(xgbase + (size_t)s * 8192 + 512, Xs + s * 1024 + 512);
        }
        asm volatile("s_waitcnt vmcnt(0)" ::: "memory");
    }
    __syncthreads();

    XF xc[4], xn[4];
    {
        const unsigned short* s = Xs;                // slot 0 = X(0)
        xc[0].u = *(const uint4*)(s + o1);
        xc[1].u = *(const uint4*)(s + o2);
        xc[2].u = *(const uint4*)(s + o3);
        xc[3].u = *(const uint4*)(s + o4);
    }

    auto reduce_one = [&](int slot, int step) __attribute__((always_inline)) {
        float cur2 = b2r;
#pragma unroll
        for (int wp = 0; wp < 16; ++wp) cur2 += Cbuf[slot][w * 1024 + wp * 64 + lane];
        m2 = fmaf(beta2r, m2, cur2);
        m2 = fmaf(spk2f, nthr2, m2);
        bool sp2 = m2 > thr2r;
        spk2f = sp2 ? 1.0f : 0.0f;
        unsigned long long mask = __ballot(sp2);
        if (lane < 4) {
            unsigned short v = (unsigned short)(mask >> (lane * 16));
            spkbits[((size_t)step * BATCH + btile * 16 + lane * 4 + w) * 32 + slice] = v;
        }
    };

    auto body = [&](int step, XF* xcur, XF* xnx) __attribute__((always_inline)) {
        // register-prefetch X(step+1) frags from ring slot (step+1)&7 (runtime index)
        {
            const unsigned short* sx = Xs + (size_t)(((step + 1) & 7) * 1024);
            xnx[0].u = *(const uint4*)(sx + o1);
            xnx[1].u = *(const uint4*)(sx + o2);
            xnx[2].u = *(const uint4*)(sx + o3);
            xnx[3].u = *(const uint4*)(sx + o4);
        }
        // GEMM1: 4-term split, 8 MFMA (C initialized directly from bias)
        f32x4 D[2];
#pragma unroll
        for (int c = 0; c < 2; ++c) {
            D[c] = __builtin_amdgcn_mfma_f32_16x16x32_bf16(A1[c], xcur[0].s, b14[c], 0, 0, 0);
            D[c] = __builtin_amdgcn_mfma_f32_16x16x32_bf16(A1[c], xcur[1].s, D[c], 0, 0, 0);
            D[c] = __builtin_amdgcn_mfma_f32_16x16x32_bf16(A2[c], xcur[2].s, D[c], 0, 0, 0);
            D[c] = __builtin_amdgcn_mfma_f32_16x16x32_bf16(A3[c], xcur[3].s, D[c], 0, 0, 0);
        }
        // LIF1 (scaled: thr == 1)
#pragma unroll
        for (int i = 0; i < 8; ++i) {
            int c = i >> 2, r = i & 3;
            float mv = fmaf(bet1[c][r], m1[i], D[c][r]);
            mv -= spk1f[i];
            bool sp = mv > 1.0f;
            m1[i] = mv;
            spk1f[i] = sp ? 1.0f : 0.0f;
        }
        // spikes pack directly into GEMM2's A-frag (k-permuted window: af[j] = spk1f[j])
        union { uint4 u; short8 s; } af;
        af.u.x = pack_hi16(__float_as_uint(spk1f[0]), __float_as_uint(spk1f[1]));
        af.u.y = pack_hi16(__float_as_uint(spk1f[2]), __float_as_uint(spk1f[3]));
        af.u.z = pack_hi16(__float_as_uint(spk1f[4]), __float_as_uint(spk1f[5]));
        af.u.w = pack_hi16(__float_as_uint(spk1f[6]), __float_as_uint(spk1f[7]));
        // GEMM2: K=32 chunk, hi then lo chained
        f32x4 C2 = { 0.f, 0.f, 0.f, 0.f };
        C2 = __builtin_amdgcn_mfma_f32_16x16x32_bf16(af.s, bhi, C2, 0, 0, 0);
        C2 = __builtin_amdgcn_mfma_f32_16x16x32_bf16(af.s, blo, C2, 0, 0, 0);
        float* cb = Cbuf[step & 3];
#pragma unroll
        for (int r = 0; r < 4; ++r)
            cb[r * 1024 + w * 64 + lane] = C2[r];
    };

#pragma unroll 1
    for (int p = 0; p < T_STEPS / 2; ++p) {
        int s0 = p << 1;
        // stager: DMA X(s0+4), X(s0+5) into ring slots (s0+4)&7, (s0+5)&7 (R2 cadence)
        if (w == 15) {
            int ta = s0 + 4; if (ta > T_STEPS - 1) ta = T_STEPS - 1;
            int tb = s0 + 5; if (tb > T_STEPS - 1) tb = T_STEPS - 1;
            const unsigned short* ga = xgbase + (size_t)ta * 8192;
            const unsigned short* gb = xgbase + (size_t)tb * 8192;
            unsigned short* la = Xs + (size_t)(((s0 + 4) & 7) * 1024);
            unsigned short* lb = Xs + (size_t)(((s0 + 5) & 7) * 1024);
            gload_lds16(ga,       la);
            gload_lds16(ga + 512, la + 512);
            gload_lds16(gb,       lb);
            gload_lds16(gb + 512, lb + 512);
        }
        // waves 0-3: reduce previous pair (steps s0-2, s0-1) while others run ahead
        if (w < 4 && p > 0) {
            reduce_one((s0 + 2) & 3, s0 - 2);
            reduce_one((s0 + 3) & 3, s0 - 1);
        }
        body(s0,     xc, xn);
        body(s0 + 1, xn, xc);
        if (w == 15) asm volatile("s_waitcnt vmcnt(0)" ::: "memory");
        LDS_BARRIER();
    }
    // epilogue: last pair (steps 254,255 -> Cbuf slots 2,3)
    if (w < 4) {
        reduce_one(2, T_STEPS - 2);
        reduce_one(3, T_STEPS - 1);
    }
}

// ---- action bit-GEMM + beta-weighted scan over t, split into 2 time-chunks ----
// grid 256 = (b 128) x (chunk 2); 512 threads = (tl 128) x (s 4): s = segment quarter.
// chunk 0 writes out[t<128] + carry[b] = mem_a(127); chunk 1 writes local scans to Lws.
__global__ __launch_bounds__(512) void k_act(
    const unsigned short* __restrict__ spkbits,
    const float* __restrict__ Wa, const float* __restrict__ ba,
    const float* __restrict__ beta_act_p, float* __restrict__ out,
    f32x4* __restrict__ Lws, f32x4* __restrict__ Cws)
{
    __shared__ f32x4 waT[512];
    __shared__ f32x4 part[512];
    __shared__ f32x4 sc[128];
    int tid = threadIdx.x;
    int b   = blockIdx.x & 127;
    int c   = blockIdx.x >> 7;
    int tl  = tid & 127;
    int s   = tid >> 7;          // 0..3
    int t   = c * 128 + tl;

    {
        f32x4 v = { Wa[tid], Wa[512 + tid], Wa[1024 + tid], Wa[1536 + tid] };
        waT[tid] = v;
    }
    float bact = fminf(fmaxf(beta_act_p[0], 0.0f), 1.0f);
    f32x4 acc;
    if (s == 0) { acc[0] = ba[0]; acc[1] = ba[1]; acc[2] = ba[2]; acc[3] = ba[3]; }
    else        { acc[0] = 0.f;   acc[1] = 0.f;   acc[2] = 0.f;   acc[3] = 0.f;   }
    __syncthreads();

    // this thread: timestep t, segments [s*8, s*8+8) (each segment = 16 j bits)
    const unsigned short* sp = spkbits + ((size_t)t * BATCH + b) * 32 + s * 8;
    uint4 v = *(const uint4*)sp;
    unsigned int wbuf[4] = { v.x, v.y, v.z, v.w };
#pragma unroll
    for (int ww = 0; ww < 4; ++ww) {
#pragma unroll
        for (int half = 0; half < 2; ++half) {
            unsigned int wd = (wbuf[ww] >> (half * 16)) & 0xFFFFu;
            int seg = s * 8 + ww * 2 + half;
#pragma unroll
            for (int i = 0; i < 16; ++i) {
                float sel = ((wd >> i) & 1u) ? 1.0f : 0.0f;
                f32x4 wv = waT[seg * 16 + i];
                acc[0] = fmaf(sel, wv[0], acc[0]);
                acc[1] = fmaf(sel, wv[1], acc[1]);
                acc[2] = fmaf(sel, wv[2], acc[2]);
                acc[3] = fmaf(sel, wv[3], acc[3]);
            }
        }
    }
    part[tid] = acc;
    __syncthreads();
    if (tid < 128) {
        f32x4 a0 = part[tid], a1 = part[tid + 128], a2 = part[tid + 256], a3 = part[tid + 384];
        f32x4 sum;
        sum[0] = ((a0[0] + a1[0]) + a2[0]) + a3[0];
        sum[1] = ((a0[1] + a1[1]) + a2[1]) + a3[1];
        sum[2] = ((a0[2] + a1[2]) + a2[2]) + a3[2];
        sum[3] = ((a0[3] + a1[3]) + a2[3]) + a3[3];
        sc[tid] = sum;
    }
    __syncthreads();
    float bd = bact;
    for (int d = 1; d < 128; d <<= 1) {
        f32x4 cv = { 0.f, 0.f, 0.f, 0.f }, pv = { 0.f, 0.f, 0.f, 0.f };
        if (tid < 128) {
            cv = sc[tid];
            if (tid >= d) pv = sc[tid - d];
        }
        __syncthreads();
        if (tid < 128) {
            cv[0] = fmaf(bd, pv[0], cv[0]);
            cv[1] = fmaf(bd, pv[1], cv[1]);
            cv[2] = fmaf(bd, pv[2], cv[2]);
            cv[3] = fmaf(bd, pv[3], cv[3]);
            sc[tid] = cv;
        }
        __syncthreads();
        bd *= bd;
    }
    if (tid < 128) {
        f32x4 res = sc[tid];
        if (c == 0) {
            *(f32x4*)(out + (size_t)t * 512 + b * 4) = res;
            if (tl == 127) Cws[b] = res;       // carry = mem_a(127)
        } else {
            Lws[b * 128 + tl] = res;           // local scan, carry applied in k_act2
        }
    }
}

// out[t=128+tl] = Lws + beta^(tl+1) * carry  (exact linear-recurrence chunk fix-up)
__global__ __launch_bounds__(128) void k_act2(
    const f32x4* __restrict__ Lws, const f32x4* __restrict__ Cws,
    const float* __restrict__ beta_act_p, float* __restrict__ out)
{
    int tl = threadIdx.x;
    int b  = blockIdx.x;
    float bact = fminf(fmaxf(beta_act_p[0], 0.0f), 1.0f);
    float p = 1.0f, base = bact;
    int e = tl + 1;
#pragma unroll
    for (int i = 0; i < 8; ++i) { if (e & 1) p *= base; base *= base; e >>= 1; }
    f32x4 L = Lws[b * 128 + tl];
    f32x4 C = Cws[b];
    f32x4 r;
    r[0] = fmaf(p, C[0], L[0]);
    r[1] = fmaf(p, C[1], L[1]);
    r[2] = fmaf(p, C[2], L[2]);
    r[3] = fmaf(p, C[3], L[3]);
    *(f32x4*)(out + (size_t)(128 + tl) * 512 + b * 4) = r;
}

extern "C" void kernel_launch(void* const* d_in, const int* in_sizes, int n_in,
                              void* d_out, int out_size, void* d_ws, size_t ws_size,
                              hipStream_t stream)
{
    const float* batch    = (const float*)d_in[0];
    const float* W1       = (const float*)d_in[1];
    const float* b1       = (const float*)d_in[2];
    const float* beta1    = (const float*)d_in[3];
    const float* thr1     = (const float*)d_in[4];
    const float* W2       = (const float*)d_in[5];
    const float* b2       = (const float*)d_in[6];
    const float* beta2    = (const float*)d_in[7];
    const float* thr2     = (const float*)d_in[8];
    const float* Wa       = (const float*)d_in[9];
    const float* ba       = (const float*)d_in[10];
    const float* beta_act = (const float*)d_in[11];
    const float* inp_min  = (const float*)d_in[12];
    const float* inp_max  = (const float*)d_in[13];
    float* out            = (float*)d_out;

    char* ws = (char*)d_ws;
    unsigned short* W2hi    = (unsigned short*)ws;                          // 512 KiB
    unsigned short* W2lo    = (unsigned short*)(ws + (512u << 10));         // 512 KiB
    unsigned short* W1rows  = (unsigned short*)(ws + (1u << 20));           // 64 KiB
    float*          b1s     = (float*)(ws + (1u << 20) + (64u << 10));      // 2 KiB
    unsigned short* Xf      = (unsigned short*)(ws + (2u << 20));           // 4 MiB (compact)
    f32x4*          Lws     = (f32x4*)(ws + (6u << 20));                    // 256 KiB
    f32x4*          Cws     = (f32x4*)(ws + (6u << 20) + (256u << 10));     // 2 KiB
    unsigned short* spkbits = (unsigned short*)(ws + (10u << 20));          // 2 MiB

    hipLaunchKernelGGL(k_prep, dim3(514), dim3(256), 0, stream,
                       W2, W1, b1, thr1, inp_min, inp_max, batch,
                       W2hi, W2lo, W1rows, b1s, Xf);
    hipLaunchKernelGGL(k_main, dim3(256), dim3(1024), 0, stream,
                       Xf, W2hi, W2lo, W1rows, b1s, beta1, b2, beta2, thr2, spkbits);
    hipLaunchKernelGGL(k_act, dim3(256), dim3(512), 0, stream,
                       spkbits, Wa, ba, beta_act, out, Lws, Cws);
    hipLaunchKernelGGL(k_act2, dim3(128), dim3(128), 0, stream, Lws, Cws, beta_act, out);
}